// Round 12
// baseline (260.878 us; speedup 1.0000x reference)
//
#include <hip/hip_runtime.h>
#include <hip/hip_bf16.h>

typedef __attribute__((ext_vector_type(4))) float  f32x4;
typedef __attribute__((ext_vector_type(8))) short  short8;
typedef __attribute__((ext_vector_type(2))) float  flt2;
typedef long long ll;

__device__ __forceinline__ short f2bf(float f) {
    __hip_bfloat16 h = __float2bfloat16(f);
    short s; __builtin_memcpy(&s, &h, 2);
    return s;
}
__device__ __forceinline__ float bf2f(short s) {
    unsigned u = ((unsigned)(unsigned short)s) << 16;
    float f; __builtin_memcpy(&f, &u, 4);
    return f;
}
__device__ __forceinline__ void gload_lds16(const void* g, void* l) {
    __builtin_amdgcn_global_load_lds(
        (const __attribute__((address_space(1))) unsigned*)(g),
        (__attribute__((address_space(3))) unsigned*)(l),
        16, 0, 0);
}

// ---------------------------------------------------------------------------
// prep: weights -> bf16 [k][co][ci]; W2t/W3t padded to 28 k-tiles (tile 27 = 0)
// ---------------------------------------------------------------------------
__global__ void prep_kernel(const float* __restrict__ W1, const float* __restrict__ W2,
                            const float* __restrict__ W3, const float* __restrict__ W4,
                            const float* __restrict__ W5,
                            short* W1t, short* W2t, short* W3t, short* W4t, short* W5t) {
    int gid = blockIdx.x * 256 + threadIdx.x;
    if (gid < 32 * 64) {                       // W1t[co][e], e=2k+ci, pad e>=54
        int co = gid >> 6, e = gid & 63;
        float v = 0.f;
        if (e < 54) { int k = e >> 1, ci = e & 1; v = W1[(k * 2 + ci) * 32 + co]; }
        W1t[gid] = f2bf(v);
        return;
    }
    int g = gid - 32 * 64;
    if (g < 28 * 2048) { int k = g / 2048, r = g % 2048, co = r >> 5, ci = r & 31;
        W2t[g] = (k < 27) ? f2bf(W2[((ll)k * 32 + ci) * 64 + co]) : (short)0; return; }
    g -= 28 * 2048;
    if (g < 28 * 8192) { int k = g / 8192, r = g % 8192, co = r >> 6, ci = r & 63;
        W3t[g] = (k < 27) ? f2bf(W3[((ll)k * 64 + ci) * 128 + co]) : (short)0; return; }
    g -= 28 * 8192;
    if (g < 8 * 64 * 128) { int k = g / (64*128), r = g % (64*128), co = r >> 7, ci = r & 127;
        W4t[g] = f2bf(W4[((ll)k * 128 + ci) * 64 + co]); return; }
    g -= 8 * 64 * 128;
    if (g < 8 * 32 * 64) { int k = g / (32*64), r = g % (32*64), co = r >> 6, ci = r & 63;
        W5t[g] = f2bf(W5[((ll)k * 64 + ci) * 32 + co]); return; }
}

// ---------------------------------------------------------------------------
// conv1 as dense MFMA GEMM + fused stats partials
// ---------------------------------------------------------------------------
__launch_bounds__(256)
__global__ void c1_kernel(const float* __restrict__ feats, const int* __restrict__ nbr,
                          const short* __restrict__ W1t, short* __restrict__ out,
                          float* __restrict__ part, int N) {
    __shared__ float sc[8 * 32];
    int tid = threadIdx.x, lane = tid & 63, wave = tid >> 6;
    int rb = blockIdx.x * 64 + wave * 16;
    int r = rb + (lane & 15);
    int rl = r < N ? r : N - 1;
    int seg = lane >> 4, l15 = lane & 15;
    f32x4 acc[2];
    acc[0] = (f32x4){0,0,0,0}; acc[1] = (f32x4){0,0,0,0};
    short8 a[2];
    #pragma unroll
    for (int kc = 0; kc < 2; ++kc) {
        #pragma unroll
        for (int j = 0; j < 4; ++j) {
            int k = kc * 16 + seg * 4 + j;
            flt2 f = (flt2){0.f, 0.f};
            if (k < 27) {
                int idx = nbr[(ll)k * N + rl];
                if (idx >= 0) f = *(const flt2*)(feats + 2 * (ll)idx);
            }
            a[kc][2*j]   = f2bf(f[0]);
            a[kc][2*j+1] = f2bf(f[1]);
        }
    }
    #pragma unroll
    for (int kc = 0; kc < 2; ++kc)
        #pragma unroll
        for (int c = 0; c < 2; ++c) {
            short8 b = *(const short8*)(W1t + (c*16 + l15) * 64 + kc * 32 + seg * 8);
            acc[c] = __builtin_amdgcn_mfma_f32_16x16x32_bf16(a[kc], b, acc[c], 0, 0, 0);
        }
    int r0 = rb + seg * 4;
    #pragma unroll
    for (int c = 0; c < 2; ++c) {
        int col = c * 16 + l15;
        #pragma unroll
        for (int j = 0; j < 4; ++j)
            if (r0 + j < N) out[(ll)(r0 + j) * 32 + col] = f2bf(acc[c][j]);
    }
    float s[2], q[2];
    #pragma unroll
    for (int c = 0; c < 2; ++c) { s[c] = 0.f; q[c] = 0.f; }
    #pragma unroll
    for (int c = 0; c < 2; ++c)
        #pragma unroll
        for (int j = 0; j < 4; ++j) {
            float v = (r0 + j < N) ? acc[c][j] : 0.f;
            s[c] += v; q[c] += v * v;
        }
    #pragma unroll
    for (int c = 0; c < 2; ++c) {
        s[c] += __shfl_xor(s[c], 16); q[c] += __shfl_xor(q[c], 16);
        s[c] += __shfl_xor(s[c], 32); q[c] += __shfl_xor(q[c], 32);
    }
    if (lane < 16) {
        #pragma unroll
        for (int c = 0; c < 2; ++c) {
            sc[(wave * 2 + 0) * 32 + c * 16 + l15] = s[c];
            sc[(wave * 2 + 1) * 32 + c * 16 + l15] = q[c];
        }
    }
    __syncthreads();
    for (int i = tid; i < 32; i += 256) {
        float ss = sc[0*32+i] + sc[2*32+i] + sc[4*32+i] + sc[6*32+i];
        float qq = sc[1*32+i] + sc[3*32+i] + sc[5*32+i] + sc[7*32+i];
        part[(ll)blockIdx.x * 64 + i]      = ss;
        part[(ll)blockIdx.x * 64 + 32 + i] = qq;
    }
}

// ---------------------------------------------------------------------------
// Sparse MFMA conv v6: PAIRED k-loop (14 periods of 2 k-offsets). Depth-1
// pair staging (2 bufs, disjoint compute/stage), A-gather loaded one FULL
// pair-period ahead (covers ~900cy scatter latency). Wait vmcnt(2*RG*KC)
// retires idx+staging, leaves A-loads in flight (R9/R10-verified invariant,
// same sched_barrier pins). Uniform body: pad weight tile 27, clamped idx.
// Fused BN-stats partials in epilogue.
// ---------------------------------------------------------------------------
template<int CIN, int COLS, int RG, int MINW>
__launch_bounds__(256, MINW)
__global__ void msconv6_kernel(const short* __restrict__ inb, const int* __restrict__ nbr,
                               const short* __restrict__ Wt, short* __restrict__ out,
                               float* __restrict__ part, int N, int zoff) {
    constexpr int KC = CIN / 32, NT = COLS / 16;
    constexpr int CPK = COLS * CIN / 8, BIT = CPK / 256;
    constexpr int WST = COLS * CIN;
    constexpr int SH = (CIN == 32) ? 6 : 7;
    __shared__ __align__(16) short lb[2][2 * WST];

    const int tid = threadIdx.x, lane = tid & 63, wave = tid >> 6;
    const int seg = lane >> 4, l15 = lane & 15;
    const int wrb = blockIdx.x * (64 * RG) + wave * (16 * RG);
    const char* inB = (const char*)inb;

    int rl[RG];
    #pragma unroll
    for (int rg = 0; rg < RG; ++rg) {
        int r = wrb + rg * 16 + l15;
        rl[rg] = r < N ? r : N - 1;
    }

    // pair p covers k = 2p, 2p+1 (k==27 clamped to 26; weight tile 27 = zeros)
    auto rawIdx2 = [&](int p, int (&ix)[2][RG]) {
        #pragma unroll
        for (int kk = 0; kk < 2; ++kk) {
            int kq = 2 * p + kk; if (kq > 26) kq = 26;
            #pragma unroll
            for (int rg = 0; rg < RG; ++rg) ix[kk][rg] = nbr[(ll)kq * N + rl[rg]];
        }
    };
    auto mkoff2 = [&](const int (&ix)[2][RG], int (&o)[2][RG]) {
        #pragma unroll
        for (int kk = 0; kk < 2; ++kk)
            #pragma unroll
            for (int rg = 0; rg < RG; ++rg)
                o[kk][rg] = (ix[kk][rg] >= 0) ? (ix[kk][rg] << SH) : zoff;
    };
    auto stage2 = [&](int p, int buf) {
        #pragma unroll
        for (int kk = 0; kk < 2; ++kk)
            #pragma unroll
            for (int it = 0; it < BIT; ++it) {
                int q = it * 256 + tid;
                int co = q % COLS, sg = (q / COLS) & 3, kc = q / (COLS * 4);
                gload_lds16(Wt + (ll)(2 * p + kk) * WST + co * CIN + kc * 32 + sg * 8,
                            &lb[buf][kk * WST + q * 8]);
            }
    };
    auto ldA2 = [&](short8 (&a)[2][RG][KC], const int (&o)[2][RG]) {
        #pragma unroll
        for (int kk = 0; kk < 2; ++kk)
            #pragma unroll
            for (int rg = 0; rg < RG; ++rg) {
                const char* base = inB + o[kk][rg];
                #pragma unroll
                for (int kc = 0; kc < KC; ++kc)
                    a[kk][rg][kc] = *(const short8*)(base + kc * 64 + seg * 16);
            }
    };

    f32x4 acc[RG][NT];
    #pragma unroll
    for (int rg = 0; rg < RG; ++rg)
        #pragma unroll
        for (int c = 0; c < NT; ++c) acc[rg][c] = (f32x4){0.f, 0.f, 0.f, 0.f};

    auto compute2 = [&](int buf, short8 (&a)[2][RG][KC]) {
        #pragma unroll
        for (int kk = 0; kk < 2; ++kk)
            #pragma unroll
            for (int kc = 0; kc < KC; ++kc)
                #pragma unroll
                for (int c = 0; c < NT; ++c) {
                    short8 b = *(const short8*)&lb[buf][kk * WST
                                + ((kc * 4 + seg) * COLS + c * 16 + l15) * 8];
                    #pragma unroll
                    for (int rg = 0; rg < RG; ++rg)
                        acc[rg][c] = __builtin_amdgcn_mfma_f32_16x16x32_bf16(
                            a[kk][rg][kc], b, acc[rg][c], 0, 0, 0);
                }
    };

    short8 aA[2][RG][KC], aB[2][RG][KC];
    int iF[2][RG], offC[2][RG];

    // prologue: stage pair0, A(pair0); idx rolled to pair2
    {
        int i0[2][RG], i1[2][RG], o0[2][RG];
        rawIdx2(0, i0); rawIdx2(1, i1); rawIdx2(2, iF);
        mkoff2(i0, o0); mkoff2(i1, offC);
        stage2(0, 0);
        __builtin_amdgcn_sched_barrier(0);
        ldA2(aA, o0);
        __builtin_amdgcn_sched_barrier(0);
        asm volatile("s_waitcnt vmcnt(%0) lgkmcnt(0)" :: "n"(2 * RG * KC) : "memory");
        __builtin_amdgcn_s_barrier();
        __builtin_amdgcn_sched_barrier(0);
    }

    #pragma unroll
    for (int p = 0; p < 14; ++p) {
        int iN[2][RG];
        {
            int pq = (p + 3 < 14) ? (p + 3) : 13;
            rawIdx2(pq, iN);
            int ps = (p + 1 < 14) ? (p + 1) : 13;    // last period: harmless restage
            stage2(ps, (p + 1) & 1);
        }
        __builtin_amdgcn_sched_barrier(0);
        if (p & 1) ldA2(aA, offC); else ldA2(aB, offC);   // A(pair p+1), newest vmem
        __builtin_amdgcn_sched_barrier(0);
        if (p & 1) compute2(1, aB); else compute2(0, aA);
        __builtin_amdgcn_sched_barrier(0);
        asm volatile("s_waitcnt vmcnt(%0) lgkmcnt(0)" :: "n"(2 * RG * KC) : "memory");
        __builtin_amdgcn_s_barrier();
        __builtin_amdgcn_sched_barrier(0);
        mkoff2(iF, offC);                                  // offsets for pair p+2
        #pragma unroll
        for (int kk = 0; kk < 2; ++kk)
            #pragma unroll
            for (int rg = 0; rg < RG; ++rg) iF[kk][rg] = iN[kk][rg];
    }

    // C-write
    #pragma unroll
    for (int rg = 0; rg < RG; ++rg)
        #pragma unroll
        for (int c = 0; c < NT; ++c) {
            int col = c * 16 + l15;
            #pragma unroll
            for (int j = 0; j < 4; ++j) {
                int rr = wrb + rg * 16 + seg * 4 + j;
                if (rr < N) out[(ll)rr * COLS + col] = f2bf(acc[rg][c][j]);
            }
        }

    // fused stats partials (fp32 acc, masked to valid rows)
    float s[NT], q[NT];
    #pragma unroll
    for (int c = 0; c < NT; ++c) { s[c] = 0.f; q[c] = 0.f; }
    #pragma unroll
    for (int rg = 0; rg < RG; ++rg)
        #pragma unroll
        for (int c = 0; c < NT; ++c)
            #pragma unroll
            for (int j = 0; j < 4; ++j) {
                int rr = wrb + rg * 16 + seg * 4 + j;
                float v = (rr < N) ? acc[rg][c][j] : 0.f;
                s[c] += v; q[c] += v * v;
            }
    #pragma unroll
    for (int c = 0; c < NT; ++c) {
        s[c] += __shfl_xor(s[c], 16); q[c] += __shfl_xor(q[c], 16);
        s[c] += __shfl_xor(s[c], 32); q[c] += __shfl_xor(q[c], 32);
    }
    float* sc = (float*)&lb[0][0];
    if (lane < 16) {
        #pragma unroll
        for (int c = 0; c < NT; ++c) {
            sc[(wave * 2 + 0) * COLS + c * 16 + l15] = s[c];
            sc[(wave * 2 + 1) * COLS + c * 16 + l15] = q[c];
        }
    }
    __syncthreads();
    for (int i = tid; i < COLS; i += 256) {
        float ss = sc[0*COLS+i] + sc[2*COLS+i] + sc[4*COLS+i] + sc[6*COLS+i];
        float qq = sc[1*COLS+i] + sc[3*COLS+i] + sc[5*COLS+i] + sc[7*COLS+i];
        part[(ll)blockIdx.x * 2 * COLS + i]        = ss;
        part[(ll)blockIdx.x * 2 * COLS + COLS + i] = qq;
    }
}

// ---------------------------------------------------------------------------
// Decoder list build
// ---------------------------------------------------------------------------
__global__ void dcount_kernel(const int* __restrict__ poff, int* __restrict__ cnt, int N) {
    __shared__ int lc[8];
    if (threadIdx.x < 8) lc[threadIdx.x] = 0;
    __syncthreads();
    int r = blockIdx.x * 256 + threadIdx.x;
    if (r < N) atomicAdd(&lc[poff[r]], 1);
    __syncthreads();
    if (threadIdx.x < 8 && lc[threadIdx.x]) atomicAdd(&cnt[threadIdx.x], lc[threadIdx.x]);
}

__global__ void dprefix_kernel(const int* __restrict__ cnt, int* __restrict__ bases,
                               int* __restrict__ kofb, int* __restrict__ perm, int nblk) {
    __shared__ int base[9];
    if (threadIdx.x == 0) {
        int b = 0;
        for (int k = 0; k < 8; ++k) { base[k] = b; b += (cnt[k] + 63) & ~63; }
        base[8] = b;
        for (int k = 0; k < 9; ++k) bases[k] = base[k];
    }
    __syncthreads();
    int nb = base[8] >> 6;
    for (int i = threadIdx.x; i < nblk; i += 256) {
        int k = -1;
        if (i < nb) {
            int rb = i << 6; k = 0;
            while (rb >= base[k + 1]) ++k;
        }
        kofb[i] = k;
    }
    for (int k = 0; k < 8; ++k) {
        int s = base[k] + cnt[k], e = base[k + 1];
        for (int i = s + threadIdx.x; i < e; i += 256) perm[i] = -1;
    }
}

__global__ void dscatter_kernel(const int* __restrict__ poff, const int* __restrict__ bases,
                                int* __restrict__ cur, int* __restrict__ perm, int N) {
    __shared__ int lc[8], lbs[8];
    if (threadIdx.x < 8) lc[threadIdx.x] = 0;
    __syncthreads();
    int r = blockIdx.x * 256 + threadIdx.x;
    int k = 0, myl = 0;
    if (r < N) { k = poff[r]; myl = atomicAdd(&lc[k], 1); }
    __syncthreads();
    if (threadIdx.x < 8) lbs[threadIdx.x] = atomicAdd(&cur[threadIdx.x], lc[threadIdx.x]);
    __syncthreads();
    if (r < N) perm[bases[k] + lbs[k] + myl] = r;
}

// ---------------------------------------------------------------------------
// Decoder gather-GEMM + fused stats (pad rows have zero acc -> no mask)
// ---------------------------------------------------------------------------
template<int CIN, int COUT>
__launch_bounds__(256)
__global__ void gdec_kernel(const short* __restrict__ inb, const int* __restrict__ perm,
                            const int* __restrict__ kofb, const int* __restrict__ pidx,
                            const short* __restrict__ Wt, const short* __restrict__ zrow,
                            short* __restrict__ out, float* __restrict__ part) {
    constexpr int KC = CIN / 32, NT = COUT / 16;
    constexpr int CPK = COUT * CIN / 8, BIT = CPK / 256;
    __shared__ __align__(16) short lb[COUT * CIN];
    const int tid = threadIdx.x, lane = tid & 63, wave = tid >> 6;
    int k = kofb[blockIdx.x];
    if (k < 0) {
        for (int i = tid; i < 2 * COUT; i += 256) part[(ll)blockIdx.x * 2 * COUT + i] = 0.f;
        return;
    }
    const int seg = lane >> 4, l15 = lane & 15;
    const int wrb = blockIdx.x * 64 + wave * 16;
    int rl = wrb + l15;
    int pr = perm[rl];
    int idx = pr < 0 ? -1 : pidx[pr];

    #pragma unroll
    for (int it = 0; it < BIT; ++it) {
        int q = it * 256 + tid;
        int co = q % COUT, sg = (q / COUT) & 3, kc = q / (COUT * 4);
        gload_lds16(Wt + ((ll)k * COUT + co) * CIN + kc * 32 + sg * 8, &lb[q * 8]);
    }
    short8 a[KC];
    const short* base = (idx < 0) ? zrow : (inb + (ll)idx * CIN);
    #pragma unroll
    for (int kc = 0; kc < KC; ++kc)
        a[kc] = *(const short8*)(base + kc * 32 + seg * 8);

    f32x4 acc[NT];
    #pragma unroll
    for (int c = 0; c < NT; ++c) acc[c] = (f32x4){0.f, 0.f, 0.f, 0.f};
    __syncthreads();
    #pragma unroll
    for (int kc = 0; kc < KC; ++kc)
        #pragma unroll
        for (int c = 0; c < NT; ++c) {
            short8 b = *(const short8*)&lb[((kc * 4 + seg) * COUT + c * 16 + l15) * 8];
            acc[c] = __builtin_amdgcn_mfma_f32_16x16x32_bf16(a[kc], b, acc[c], 0, 0, 0);
        }
    #pragma unroll
    for (int j = 0; j < 4; ++j) {
        int prs = __shfl(pr, seg * 4 + j, 64);
        if (prs >= 0) {
            #pragma unroll
            for (int c = 0; c < NT; ++c)
                out[(ll)prs * COUT + c * 16 + l15] = f2bf(acc[c][j]);
        }
    }
    float s[NT], q[NT];
    #pragma unroll
    for (int c = 0; c < NT; ++c) { s[c] = 0.f; q[c] = 0.f; }
    #pragma unroll
    for (int c = 0; c < NT; ++c)
        #pragma unroll
        for (int j = 0; j < 4; ++j) { float v = acc[c][j]; s[c] += v; q[c] += v * v; }
    #pragma unroll
    for (int c = 0; c < NT; ++c) {
        s[c] += __shfl_xor(s[c], 16); q[c] += __shfl_xor(q[c], 16);
        s[c] += __shfl_xor(s[c], 32); q[c] += __shfl_xor(q[c], 32);
    }
    __syncthreads();
    float* sc = (float*)lb;
    if (lane < 16) {
        #pragma unroll
        for (int c = 0; c < NT; ++c) {
            sc[(wave * 2 + 0) * COUT + c * 16 + l15] = s[c];
            sc[(wave * 2 + 1) * COUT + c * 16 + l15] = q[c];
        }
    }
    __syncthreads();
    for (int i = tid; i < COUT; i += 256) {
        float ss = sc[0*COUT+i] + sc[2*COUT+i] + sc[4*COUT+i] + sc[6*COUT+i];
        float qq = sc[1*COUT+i] + sc[3*COUT+i] + sc[5*COUT+i] + sc[7*COUT+i];
        part[(ll)blockIdx.x * 2 * COUT + i]        = ss;
        part[(ll)blockIdx.x * 2 * COUT + COUT + i] = qq;
    }
}

// ---------------------------------------------------------------------------
// red2: variable-nblk deterministic reduce -> BN scale/shift
// ---------------------------------------------------------------------------
__global__ void red2_kernel(const float* __restrict__ part, int nblk,
                            const float* __restrict__ g, const float* __restrict__ bb,
                            float* __restrict__ A, float* __restrict__ B, int C, int N) {
    int c = blockIdx.x;
    float s = 0.f, q = 0.f;
    for (int i = threadIdx.x; i < nblk; i += 256) {
        s += part[(ll)i * 2 * C + c];
        q += part[(ll)i * 2 * C + C + c];
    }
    __shared__ float ls[256], lq[256];
    ls[threadIdx.x] = s; lq[threadIdx.x] = q;
    __syncthreads();
    for (int str = 128; str >= 1; str >>= 1) {
        if (threadIdx.x < str) {
            ls[threadIdx.x] += ls[threadIdx.x + str];
            lq[threadIdx.x] += lq[threadIdx.x + str];
        }
        __syncthreads();
    }
    if (threadIdx.x == 0) {
        float inv = 1.0f / (float)N;
        float mu = ls[0] * inv, var = lq[0] * inv - mu * mu;
        float a = g[c] * rsqrtf(var + 1e-5f);
        A[c] = a; B[c] = bb[c] - mu * a;
    }
}

template<int C>
__global__ void bnrelu_kernel(const short* __restrict__ x, const float* __restrict__ A,
                              const float* __restrict__ B, short* __restrict__ out, int N) {
    constexpr int CPR = C / 8;
    int i = blockIdx.x * 256 + threadIdx.x;
    if (i >= N * CPR) return;
    int r = i / CPR, ch = i - r * CPR;
    short8 v = *(const short8*)(x + (ll)r * C + ch * 8);
    short8 o;
    #pragma unroll
    for (int j = 0; j < 8; ++j) {
        int c = ch * 8 + j;
        float y = fmaf(bf2f(v[j]), A[c], B[c]);
        o[j] = f2bf(y > 0.f ? y : 0.f);
    }
    *(short8*)(out + (ll)r * C + ch * 8) = o;
}

__global__ void outk_kernel(const short* __restrict__ z, const float* __restrict__ A,
                            const float* __restrict__ B, const float* __restrict__ Wout,
                            float* __restrict__ out, int N) {
    __shared__ float w[64], sa[32], sb[32];
    if (threadIdx.x < 64) w[threadIdx.x] = Wout[threadIdx.x];
    if (threadIdx.x < 32) { sa[threadIdx.x] = A[threadIdx.x]; sb[threadIdx.x] = B[threadIdx.x]; }
    __syncthreads();
    int r = blockIdx.x * 256 + threadIdx.x;
    if (r >= N) return;
    const short* zp = z + (ll)r * 32;
    float o0 = 0.f, o1 = 0.f;
    #pragma unroll
    for (int s4 = 0; s4 < 4; ++s4) {
        short8 v = *(const short8*)(zp + s4 * 8);
        #pragma unroll
        for (int j = 0; j < 8; ++j) {
            int c = s4 * 8 + j;
            float y = fmaf(bf2f(v[j]), sa[c], sb[c]);
            y = y > 0.f ? y : 0.f;
            o0 = fmaf(y, w[2*c], o0);
            o1 = fmaf(y, w[2*c+1], o1);
        }
    }
    out[(ll)r * 2]     = o0;
    out[(ll)r * 2 + 1] = o1;
}

extern "C" void kernel_launch(void* const* d_in, const int* in_sizes, int n_in,
                              void* d_out, int out_size, void* d_ws, size_t ws_size,
                              hipStream_t stream) {
    const float* feats = (const float*)d_in[0];
    const float* W1 = (const float*)d_in[1];
    const float* W2 = (const float*)d_in[2];
    const float* W3 = (const float*)d_in[3];
    const float* W4 = (const float*)d_in[4];
    const float* W5 = (const float*)d_in[5];
    const float* Wout = (const float*)d_in[6];
    const float* g1 = (const float*)d_in[7],  *b1 = (const float*)d_in[8];
    const float* g2 = (const float*)d_in[9],  *b2 = (const float*)d_in[10];
    const float* g3 = (const float*)d_in[11], *b3 = (const float*)d_in[12];
    const float* g4 = (const float*)d_in[13], *b4 = (const float*)d_in[14];
    const float* g5 = (const float*)d_in[15], *b5 = (const float*)d_in[16];
    const int* nbr0 = (const int*)d_in[17];
    const int* nbr1 = (const int*)d_in[18];
    const int* nbr2 = (const int*)d_in[19];
    const int* up1_idx = (const int*)d_in[20];
    const int* up1_off = (const int*)d_in[21];
    const int* up0_idx = (const int*)d_in[22];
    const int* up0_off = (const int*)d_in[23];

    const int N0 = in_sizes[0] / 2;
    const int N1 = in_sizes[20];
    const int N2 = in_sizes[19] / 27;

    char* cur = (char*)d_ws;
    auto alloc = [&](size_t bytes) { char* p = cur; cur += (bytes + 255) & ~255ULL; return p; };
    auto cdiv = [](ll a, ll b) { return (int)((a + b - 1) / b); };

    float* stats = (float*)alloc(4096);
    float* A1 = stats,       *B1c = stats + 32;
    float* A2 = stats + 64,  *B2c = stats + 128;
    float* A3 = stats + 192, *B3c = stats + 320;
    float* A4 = stats + 448, *B4c = stats + 512;
    float* A5 = stats + 576, *B5c = stats + 608;
    short* zrow  = (short*)((char*)stats + 2560);   // 256 bf16 zeros
    int*   cnt4  = (int*)((char*)stats + 3072);
    int*   cur4  = (int*)((char*)stats + 3104);
    int*   cnt5  = (int*)((char*)stats + 3136);
    int*   cur5  = (int*)((char*)stats + 3168);
    int*   bas4  = (int*)((char*)stats + 3200);
    int*   bas5  = (int*)((char*)stats + 3264);

    float* part = (float*)alloc(2 * 1024 * 1024);   // per-block stats partials

    size_t zmax = (size_t)N1 * 64;
    if ((size_t)N0 * 32  > zmax) zmax = (size_t)N0 * 32;
    if ((size_t)N2 * 128 > zmax) zmax = (size_t)N2 * 128;
    short* zb  = (short*)alloc(zmax * 2);
    short* e1b = (short*)alloc((size_t)N0 * 32 * 2);
    short* e2b = (short*)alloc((size_t)N1 * 64 * 2);
    short* e3b = (short*)alloc((size_t)N2 * 128 * 2);
    short* d2b = (short*)alloc((size_t)N1 * 64 * 2);
    short* W1t = (short*)alloc(32 * 64 * 2);
    short* W2t = (short*)alloc((size_t)28 * 64 * 32 * 2);    // 28 k-tiles (27 = zeros)
    short* W3t = (short*)alloc((size_t)28 * 128 * 64 * 2);
    short* W4t = (short*)alloc((size_t)8 * 64 * 128 * 2);
    short* W5t = (short*)alloc((size_t)8 * 32 * 64 * 2);

    const int gridL4 = cdiv((ll)N1 + 512, 64);
    const int gridL5 = cdiv((ll)N0 + 512, 64);
    int* perm4 = (int*)alloc((size_t)gridL4 * 64 * 4);
    int* kofb4 = (int*)alloc((size_t)gridL4 * 4);
    int* perm5 = (int*)alloc((size_t)gridL5 * 64 * 4);
    int* kofb5 = (int*)alloc((size_t)gridL5 * 4);

    const int zoff1 = (int)((ll)((char*)zrow - (char*)e1b));
    const int zoff2 = (int)((ll)((char*)zrow - (char*)e2b));

    const int nblk1 = cdiv(N0, 64);
    const int nblk2 = cdiv(N1, 128);
    const int nblk3 = cdiv(N2, 128);

    hipMemsetAsync((char*)stats + 2560, 0, 640, stream);

    prep_kernel<<<cdiv(2048 + 28*2048 + 28*8192 + 65536 + 16384, 256), 256, 0, stream>>>(
        W1, W2, W3, W4, W5, W1t, W2t, W3t, W4t, W5t);

    dcount_kernel<<<cdiv(N1, 256), 256, 0, stream>>>(up1_off, cnt4, N1);
    dprefix_kernel<<<1, 256, 0, stream>>>(cnt4, bas4, kofb4, perm4, gridL4);
    dscatter_kernel<<<cdiv(N1, 256), 256, 0, stream>>>(up1_off, bas4, cur4, perm4, N1);
    dcount_kernel<<<cdiv(N0, 256), 256, 0, stream>>>(up0_off, cnt5, N0);
    dprefix_kernel<<<1, 256, 0, stream>>>(cnt5, bas5, kofb5, perm5, gridL5);
    dscatter_kernel<<<cdiv(N0, 256), 256, 0, stream>>>(up0_off, bas5, cur5, perm5, N0);

    // L1
    c1_kernel<<<nblk1, 256, 0, stream>>>(feats, nbr0, W1t, zb, part, N0);
    red2_kernel<<<32, 256, 0, stream>>>(part, nblk1, g1, b1, A1, B1c, 32, N0);
    bnrelu_kernel<32><<<cdiv((ll)N0 * 4, 256), 256, 0, stream>>>(zb, A1, B1c, e1b, N0);

    // L2: 128 rows x 64 cols, RG=2, paired k-loop
    msconv6_kernel<32, 64, 2, 4><<<nblk2, 256, 0, stream>>>(e1b, nbr1, W2t, zb, part, N1, zoff1);
    red2_kernel<<<64, 256, 0, stream>>>(part, nblk2, g2, b2, A2, B2c, 64, N1);
    bnrelu_kernel<64><<<cdiv((ll)N1 * 8, 256), 256, 0, stream>>>(zb, A2, B2c, e2b, N1);

    // L3: 128 rows x 128 cols, RG=2, paired k-loop
    msconv6_kernel<64, 128, 2, 2><<<nblk3, 256, 0, stream>>>(e2b, nbr2, W3t, zb, part, N2, zoff2);
    red2_kernel<<<128, 256, 0, stream>>>(part, nblk3, g3, b3, A3, B3c, 128, N2);
    bnrelu_kernel<128><<<cdiv((ll)N2 * 16, 256), 256, 0, stream>>>(zb, A3, B3c, e3b, N2);

    // L4
    gdec_kernel<128, 64><<<gridL4, 256, 0, stream>>>(e3b, perm4, kofb4, up1_idx, W4t, zrow, zb, part);
    red2_kernel<<<64, 256, 0, stream>>>(part, gridL4, g4, b4, A4, B4c, 64, N1);
    bnrelu_kernel<64><<<cdiv((ll)N1 * 8, 256), 256, 0, stream>>>(zb, A4, B4c, d2b, N1);

    // L5
    gdec_kernel<64, 32><<<gridL5, 256, 0, stream>>>(d2b, perm5, kofb5, up0_idx, W5t, zrow, zb, part);
    red2_kernel<<<32, 256, 0, stream>>>(part, gridL5, g5, b5, A5, B5c, 32, N0);
    outk_kernel<<<cdiv(N0, 256), 256, 0, stream>>>(zb, A5, B5c, Wout, (float*)d_out, N0);
}

// Round 13
// 240.849 us; speedup vs baseline: 1.0832x; 1.0832x over previous
//
#include <hip/hip_runtime.h>
#include <hip/hip_bf16.h>

typedef __attribute__((ext_vector_type(4))) float  f32x4;
typedef __attribute__((ext_vector_type(8))) short  short8;
typedef __attribute__((ext_vector_type(2))) float  flt2;
typedef long long ll;

__device__ __forceinline__ short f2bf(float f) {
    __hip_bfloat16 h = __float2bfloat16(f);
    short s; __builtin_memcpy(&s, &h, 2);
    return s;
}
__device__ __forceinline__ float bf2f(short s) {
    unsigned u = ((unsigned)(unsigned short)s) << 16;
    float f; __builtin_memcpy(&f, &u, 4);
    return f;
}
__device__ __forceinline__ void gload_lds16(const void* g, void* l) {
    __builtin_amdgcn_global_load_lds(
        (const __attribute__((address_space(1))) unsigned*)(g),
        (__attribute__((address_space(3))) unsigned*)(l),
        16, 0, 0);
}
// bijective XCD swizzle (m204): contiguous grid chunks per XCD
__device__ __forceinline__ int xcd_swz(int bid, int nwg) {
    int q8 = nwg >> 3, r8 = nwg & 7;
    int xcd = bid & 7, j = bid >> 3;
    return (xcd < r8 ? xcd * (q8 + 1) : r8 * (q8 + 1) + (xcd - r8) * q8) + j;
}

// ---------------------------------------------------------------------------
// prep: weights -> bf16 [k][co][ci]; W2t/W3t padded to 28 k-tiles (tile 27 = 0)
// ---------------------------------------------------------------------------
__global__ void prep_kernel(const float* __restrict__ W1, const float* __restrict__ W2,
                            const float* __restrict__ W3, const float* __restrict__ W4,
                            const float* __restrict__ W5,
                            short* W1t, short* W2t, short* W3t, short* W4t, short* W5t) {
    int gid = blockIdx.x * 256 + threadIdx.x;
    if (gid < 32 * 64) {                       // W1t[co][e], e=2k+ci, pad e>=54
        int co = gid >> 6, e = gid & 63;
        float v = 0.f;
        if (e < 54) { int k = e >> 1, ci = e & 1; v = W1[(k * 2 + ci) * 32 + co]; }
        W1t[gid] = f2bf(v);
        return;
    }
    int g = gid - 32 * 64;
    if (g < 28 * 2048) { int k = g / 2048, r = g % 2048, co = r >> 5, ci = r & 31;
        W2t[g] = (k < 27) ? f2bf(W2[((ll)k * 32 + ci) * 64 + co]) : (short)0; return; }
    g -= 28 * 2048;
    if (g < 28 * 8192) { int k = g / 8192, r = g % 8192, co = r >> 6, ci = r & 63;
        W3t[g] = (k < 27) ? f2bf(W3[((ll)k * 64 + ci) * 128 + co]) : (short)0; return; }
    g -= 28 * 8192;
    if (g < 8 * 64 * 128) { int k = g / (64*128), r = g % (64*128), co = r >> 7, ci = r & 127;
        W4t[g] = f2bf(W4[((ll)k * 128 + ci) * 64 + co]); return; }
    g -= 8 * 64 * 128;
    if (g < 8 * 32 * 64) { int k = g / (32*64), r = g % (32*64), co = r >> 6, ci = r & 63;
        W5t[g] = f2bf(W5[((ll)k * 64 + ci) * 32 + co]); return; }
}

// ---------------------------------------------------------------------------
// conv1 as dense MFMA GEMM + fused stats partials (XCD-swizzled)
// ---------------------------------------------------------------------------
__launch_bounds__(256)
__global__ void c1_kernel(const float* __restrict__ feats, const int* __restrict__ nbr,
                          const short* __restrict__ W1t, short* __restrict__ out,
                          float* __restrict__ part, int N) {
    __shared__ float sc[8 * 32];
    const int wgid = xcd_swz(blockIdx.x, gridDim.x);
    int tid = threadIdx.x, lane = tid & 63, wave = tid >> 6;
    int rb = wgid * 64 + wave * 16;
    int r = rb + (lane & 15);
    int rl = r < N ? r : N - 1;
    int seg = lane >> 4, l15 = lane & 15;
    f32x4 acc[2];
    acc[0] = (f32x4){0,0,0,0}; acc[1] = (f32x4){0,0,0,0};
    short8 a[2];
    #pragma unroll
    for (int kc = 0; kc < 2; ++kc) {
        #pragma unroll
        for (int j = 0; j < 4; ++j) {
            int k = kc * 16 + seg * 4 + j;
            flt2 f = (flt2){0.f, 0.f};
            if (k < 27) {
                int idx = nbr[(ll)k * N + rl];
                if (idx >= 0) f = *(const flt2*)(feats + 2 * (ll)idx);
            }
            a[kc][2*j]   = f2bf(f[0]);
            a[kc][2*j+1] = f2bf(f[1]);
        }
    }
    #pragma unroll
    for (int kc = 0; kc < 2; ++kc)
        #pragma unroll
        for (int c = 0; c < 2; ++c) {
            short8 b = *(const short8*)(W1t + (c*16 + l15) * 64 + kc * 32 + seg * 8);
            acc[c] = __builtin_amdgcn_mfma_f32_16x16x32_bf16(a[kc], b, acc[c], 0, 0, 0);
        }
    int r0 = rb + seg * 4;
    #pragma unroll
    for (int c = 0; c < 2; ++c) {
        int col = c * 16 + l15;
        #pragma unroll
        for (int j = 0; j < 4; ++j)
            if (r0 + j < N) out[(ll)(r0 + j) * 32 + col] = f2bf(acc[c][j]);
    }
    float s[2], q[2];
    #pragma unroll
    for (int c = 0; c < 2; ++c) { s[c] = 0.f; q[c] = 0.f; }
    #pragma unroll
    for (int c = 0; c < 2; ++c)
        #pragma unroll
        for (int j = 0; j < 4; ++j) {
            float v = (r0 + j < N) ? acc[c][j] : 0.f;
            s[c] += v; q[c] += v * v;
        }
    #pragma unroll
    for (int c = 0; c < 2; ++c) {
        s[c] += __shfl_xor(s[c], 16); q[c] += __shfl_xor(q[c], 16);
        s[c] += __shfl_xor(s[c], 32); q[c] += __shfl_xor(q[c], 32);
    }
    if (lane < 16) {
        #pragma unroll
        for (int c = 0; c < 2; ++c) {
            sc[(wave * 2 + 0) * 32 + c * 16 + l15] = s[c];
            sc[(wave * 2 + 1) * 32 + c * 16 + l15] = q[c];
        }
    }
    __syncthreads();
    for (int i = tid; i < 32; i += 256) {
        float ss = sc[0*32+i] + sc[2*32+i] + sc[4*32+i] + sc[6*32+i];
        float qq = sc[1*32+i] + sc[3*32+i] + sc[5*32+i] + sc[7*32+i];
        part[(ll)wgid * 64 + i]      = ss;
        part[(ll)wgid * 64 + 32 + i] = qq;
    }
}

// ---------------------------------------------------------------------------
// Sparse MFMA conv v7 = R10's best schedule (depth-1 per-k staging, pinned
// counted-vmcnt, rolling scalar idx pipeline) + fused stats + XCD swizzle.
// ---------------------------------------------------------------------------
template<int CIN, int COLS, int RG, int MINW>
__launch_bounds__(256, MINW)
__global__ void msconv7_kernel(const short* __restrict__ inb, const int* __restrict__ nbr,
                               const short* __restrict__ Wt, short* __restrict__ out,
                               float* __restrict__ part, int N, int zoff) {
    constexpr int KC = CIN / 32, NT = COLS / 16;
    constexpr int CPK = COLS * CIN / 8, BIT = CPK / 256;
    constexpr int WST = COLS * CIN;
    constexpr int SH = (CIN == 32) ? 6 : 7;
    __shared__ __align__(16) short lb[2][WST];

    const int wgid = xcd_swz(blockIdx.x, gridDim.x);
    const int tid = threadIdx.x, lane = tid & 63, wave = tid >> 6;
    const int seg = lane >> 4, l15 = lane & 15;
    const int wrb = wgid * (64 * RG) + wave * (16 * RG);
    const char* inB = (const char*)inb;

    int rl[RG];
    #pragma unroll
    for (int rg = 0; rg < RG; ++rg) {
        int r = wrb + rg * 16 + l15;
        rl[rg] = r < N ? r : N - 1;
    }

    auto rawIdx = [&](int k, int (&ix)[RG]) {
        #pragma unroll
        for (int rg = 0; rg < RG; ++rg) ix[rg] = nbr[(ll)k * N + rl[rg]];
    };
    auto mkoff = [&](const int (&ix)[RG], int (&o)[RG]) {
        #pragma unroll
        for (int rg = 0; rg < RG; ++rg) o[rg] = (ix[rg] >= 0) ? (ix[rg] << SH) : zoff;
    };
    auto stage = [&](int kn, int buf) {
        #pragma unroll
        for (int it = 0; it < BIT; ++it) {
            int q = it * 256 + tid;
            int co = q % COLS, sg = (q / COLS) & 3, kc = q / (COLS * 4);
            gload_lds16(Wt + (ll)kn * WST + co * CIN + kc * 32 + sg * 8, &lb[buf][q * 8]);
        }
    };
    auto ldA = [&](short8 (&a)[RG][KC], const int (&o)[RG]) {
        #pragma unroll
        for (int rg = 0; rg < RG; ++rg) {
            const char* base = inB + o[rg];
            #pragma unroll
            for (int kc = 0; kc < KC; ++kc)
                a[rg][kc] = *(const short8*)(base + kc * 64 + seg * 16);
        }
    };

    f32x4 acc[RG][NT];
    #pragma unroll
    for (int rg = 0; rg < RG; ++rg)
        #pragma unroll
        for (int c = 0; c < NT; ++c) acc[rg][c] = (f32x4){0.f, 0.f, 0.f, 0.f};

    auto compute = [&](int buf, short8 (&a)[RG][KC]) {
        #pragma unroll
        for (int kc = 0; kc < KC; ++kc)
            #pragma unroll
            for (int c = 0; c < NT; ++c) {
                short8 b = *(const short8*)&lb[buf][((kc * 4 + seg) * COLS + c * 16 + l15) * 8];
                #pragma unroll
                for (int rg = 0; rg < RG; ++rg)
                    acc[rg][c] = __builtin_amdgcn_mfma_f32_16x16x32_bf16(
                        a[rg][kc], b, acc[rg][c], 0, 0, 0);
            }
    };

    short8 aA[RG][KC], aB[RG][KC];
    int iF[RG], offC[RG];

    {
        int i0[RG], i1[RG], o0[RG];
        rawIdx(0, i0); rawIdx(1, i1); rawIdx(2, iF);
        mkoff(i0, o0); mkoff(i1, offC);
        stage(0, 0);
        __builtin_amdgcn_sched_barrier(0);
        ldA(aA, o0);
        __builtin_amdgcn_sched_barrier(0);
        asm volatile("s_waitcnt vmcnt(%0) lgkmcnt(0)" :: "n"(RG * KC) : "memory");
        __builtin_amdgcn_s_barrier();
        __builtin_amdgcn_sched_barrier(0);
    }

    #pragma unroll
    for (int k = 0; k < 27; ++k) {
        int iN[RG];
        if (k + 1 < 27) {
            if (k + 3 < 27) rawIdx(k + 3, iN);          // oldest vmem this period
            __builtin_amdgcn_sched_barrier(0);
            stage(k + 1, (k + 1) & 1);
            __builtin_amdgcn_sched_barrier(0);
            if (k & 1) ldA(aA, offC); else ldA(aB, offC);   // newest: RG*KC A-loads
            __builtin_amdgcn_sched_barrier(0);
        }
        if (k & 1) compute(1, aB); else compute(0, aA);
        if (k + 1 < 27) {
            __builtin_amdgcn_sched_barrier(0);
            asm volatile("s_waitcnt vmcnt(%0) lgkmcnt(0)" :: "n"(RG * KC) : "memory");
            __builtin_amdgcn_s_barrier();
            __builtin_amdgcn_sched_barrier(0);
            mkoff(iF, offC);                         // offsets for period k+1's ldA
            if (k + 3 < 27) {
                #pragma unroll
                for (int rg = 0; rg < RG; ++rg) iF[rg] = iN[rg];
            }
        }
    }

    // C-write
    #pragma unroll
    for (int rg = 0; rg < RG; ++rg)
        #pragma unroll
        for (int c = 0; c < NT; ++c) {
            int col = c * 16 + l15;
            #pragma unroll
            for (int j = 0; j < 4; ++j) {
                int rr = wrb + rg * 16 + seg * 4 + j;
                if (rr < N) out[(ll)rr * COLS + col] = f2bf(acc[rg][c][j]);
            }
        }

    // fused stats partials (fp32 acc, masked to valid rows)
    float s[NT], q[NT];
    #pragma unroll
    for (int c = 0; c < NT; ++c) { s[c] = 0.f; q[c] = 0.f; }
    #pragma unroll
    for (int rg = 0; rg < RG; ++rg)
        #pragma unroll
        for (int c = 0; c < NT; ++c)
            #pragma unroll
            for (int j = 0; j < 4; ++j) {
                int rr = wrb + rg * 16 + seg * 4 + j;
                float v = (rr < N) ? acc[rg][c][j] : 0.f;
                s[c] += v; q[c] += v * v;
            }
    #pragma unroll
    for (int c = 0; c < NT; ++c) {
        s[c] += __shfl_xor(s[c], 16); q[c] += __shfl_xor(q[c], 16);
        s[c] += __shfl_xor(s[c], 32); q[c] += __shfl_xor(q[c], 32);
    }
    __syncthreads();               // k=26 period has no trailing barrier; lb reused below
    float* sc = (float*)&lb[0][0];
    if (lane < 16) {
        #pragma unroll
        for (int c = 0; c < NT; ++c) {
            sc[(wave * 2 + 0) * COLS + c * 16 + l15] = s[c];
            sc[(wave * 2 + 1) * COLS + c * 16 + l15] = q[c];
        }
    }
    __syncthreads();
    for (int i = tid; i < COLS; i += 256) {
        float ss = sc[0*COLS+i] + sc[2*COLS+i] + sc[4*COLS+i] + sc[6*COLS+i];
        float qq = sc[1*COLS+i] + sc[3*COLS+i] + sc[5*COLS+i] + sc[7*COLS+i];
        part[(ll)wgid * 2 * COLS + i]        = ss;
        part[(ll)wgid * 2 * COLS + COLS + i] = qq;
    }
}

// ---------------------------------------------------------------------------
// Decoder list build (merged: grid.y=2 selects decoder 4 / 5)
// ---------------------------------------------------------------------------
__global__ void dcountB_kernel(const int* __restrict__ poffA, int NA, int* __restrict__ cntA,
                               const int* __restrict__ poffB, int NB, int* __restrict__ cntB) {
    const int* poff = blockIdx.y ? poffB : poffA;
    int* cnt = blockIdx.y ? cntB : cntA;
    int N = blockIdx.y ? NB : NA;
    __shared__ int lc[8];
    if (threadIdx.x < 8) lc[threadIdx.x] = 0;
    __syncthreads();
    int r = blockIdx.x * 256 + threadIdx.x;
    if (r < N) atomicAdd(&lc[poff[r]], 1);
    __syncthreads();
    if (threadIdx.x < 8 && lc[threadIdx.x]) atomicAdd(&cnt[threadIdx.x], lc[threadIdx.x]);
}

__global__ void dprefixB_kernel(const int* __restrict__ cntA, int* basesA, int* kofbA,
                                int* permA, int nblkA,
                                const int* __restrict__ cntB, int* basesB, int* kofbB,
                                int* permB, int nblkB) {
    const int* cnt = blockIdx.x ? cntB : cntA;
    int* bases = blockIdx.x ? basesB : basesA;
    int* kofb  = blockIdx.x ? kofbB  : kofbA;
    int* perm  = blockIdx.x ? permB  : permA;
    int nblk   = blockIdx.x ? nblkB  : nblkA;
    __shared__ int base[9];
    if (threadIdx.x == 0) {
        int b = 0;
        for (int k = 0; k < 8; ++k) { base[k] = b; b += (cnt[k] + 63) & ~63; }
        base[8] = b;
        for (int k = 0; k < 9; ++k) bases[k] = base[k];
    }
    __syncthreads();
    int nb = base[8] >> 6;
    for (int i = threadIdx.x; i < nblk; i += 256) {
        int k = -1;
        if (i < nb) {
            int rb = i << 6; k = 0;
            while (rb >= base[k + 1]) ++k;
        }
        kofb[i] = k;
    }
    for (int k = 0; k < 8; ++k) {
        int s = base[k] + cnt[k], e = base[k + 1];
        for (int i = s + threadIdx.x; i < e; i += 256) perm[i] = -1;
    }
}

__global__ void dscatterB_kernel(const int* __restrict__ poffA, const int* basesA,
                                 int* curA, int* permA, int NA,
                                 const int* __restrict__ poffB, const int* basesB,
                                 int* curB, int* permB, int NB) {
    const int* poff = blockIdx.y ? poffB : poffA;
    const int* bases = blockIdx.y ? basesB : basesA;
    int* curp = blockIdx.y ? curB : curA;
    int* perm = blockIdx.y ? permB : permA;
    int N = blockIdx.y ? NB : NA;
    __shared__ int lc[8], lbs[8];
    if (threadIdx.x < 8) lc[threadIdx.x] = 0;
    __syncthreads();
    int r = blockIdx.x * 256 + threadIdx.x;
    int k = 0, myl = 0;
    if (r < N) { k = poff[r]; myl = atomicAdd(&lc[k], 1); }
    __syncthreads();
    if (threadIdx.x < 8) lbs[threadIdx.x] = atomicAdd(&curp[threadIdx.x], lc[threadIdx.x]);
    __syncthreads();
    if (r < N) perm[bases[k] + lbs[k] + myl] = r;
}

// ---------------------------------------------------------------------------
// Decoder gather-GEMM + fused stats + XCD swizzle
// ---------------------------------------------------------------------------
template<int CIN, int COUT>
__launch_bounds__(256)
__global__ void gdec_kernel(const short* __restrict__ inb, const int* __restrict__ perm,
                            const int* __restrict__ kofb, const int* __restrict__ pidx,
                            const short* __restrict__ Wt, const short* __restrict__ zrow,
                            short* __restrict__ out, float* __restrict__ part) {
    constexpr int KC = CIN / 32, NT = COUT / 16;
    constexpr int CPK = COUT * CIN / 8, BIT = CPK / 256;
    __shared__ __align__(16) short lb[COUT * CIN];
    const int wgid = xcd_swz(blockIdx.x, gridDim.x);
    const int tid = threadIdx.x, lane = tid & 63, wave = tid >> 6;
    int k = kofb[wgid];
    if (k < 0) {
        for (int i = tid; i < 2 * COUT; i += 256) part[(ll)wgid * 2 * COUT + i] = 0.f;
        return;
    }
    const int seg = lane >> 4, l15 = lane & 15;
    const int wrb = wgid * 64 + wave * 16;
    int rl = wrb + l15;
    int pr = perm[rl];
    int idx = pr < 0 ? -1 : pidx[pr];

    #pragma unroll
    for (int it = 0; it < BIT; ++it) {
        int q = it * 256 + tid;
        int co = q % COUT, sg = (q / COUT) & 3, kc = q / (COUT * 4);
        gload_lds16(Wt + ((ll)k * COUT + co) * CIN + kc * 32 + sg * 8, &lb[q * 8]);
    }
    short8 a[KC];
    const short* base = (idx < 0) ? zrow : (inb + (ll)idx * CIN);
    #pragma unroll
    for (int kc = 0; kc < KC; ++kc)
        a[kc] = *(const short8*)(base + kc * 32 + seg * 8);

    f32x4 acc[NT];
    #pragma unroll
    for (int c = 0; c < NT; ++c) acc[c] = (f32x4){0.f, 0.f, 0.f, 0.f};
    __syncthreads();
    #pragma unroll
    for (int kc = 0; kc < KC; ++kc)
        #pragma unroll
        for (int c = 0; c < NT; ++c) {
            short8 b = *(const short8*)&lb[((kc * 4 + seg) * COUT + c * 16 + l15) * 8];
            acc[c] = __builtin_amdgcn_mfma_f32_16x16x32_bf16(a[kc], b, acc[c], 0, 0, 0);
        }
    #pragma unroll
    for (int j = 0; j < 4; ++j) {
        int prs = __shfl(pr, seg * 4 + j, 64);
        if (prs >= 0) {
            #pragma unroll
            for (int c = 0; c < NT; ++c)
                out[(ll)prs * COUT + c * 16 + l15] = f2bf(acc[c][j]);
        }
    }
    float s[NT], q[NT];
    #pragma unroll
    for (int c = 0; c < NT; ++c) { s[c] = 0.f; q[c] = 0.f; }
    #pragma unroll
    for (int c = 0; c < NT; ++c)
        #pragma unroll
        for (int j = 0; j < 4; ++j) { float v = acc[c][j]; s[c] += v; q[c] += v * v; }
    #pragma unroll
    for (int c = 0; c < NT; ++c) {
        s[c] += __shfl_xor(s[c], 16); q[c] += __shfl_xor(q[c], 16);
        s[c] += __shfl_xor(s[c], 32); q[c] += __shfl_xor(q[c], 32);
    }
    __syncthreads();
    float* sc = (float*)lb;
    if (lane < 16) {
        #pragma unroll
        for (int c = 0; c < NT; ++c) {
            sc[(wave * 2 + 0) * COUT + c * 16 + l15] = s[c];
            sc[(wave * 2 + 1) * COUT + c * 16 + l15] = q[c];
        }
    }
    __syncthreads();
    for (int i = tid; i < COUT; i += 256) {
        float ss = sc[0*COUT+i] + sc[2*COUT+i] + sc[4*COUT+i] + sc[6*COUT+i];
        float qq = sc[1*COUT+i] + sc[3*COUT+i] + sc[5*COUT+i] + sc[7*COUT+i];
        part[(ll)wgid * 2 * COUT + i]        = ss;
        part[(ll)wgid * 2 * COUT + COUT + i] = qq;
    }
}

// ---------------------------------------------------------------------------
// red2: variable-nblk deterministic reduce -> BN scale/shift
// ---------------------------------------------------------------------------
__global__ void red2_kernel(const float* __restrict__ part, int nblk,
                            const float* __restrict__ g, const float* __restrict__ bb,
                            float* __restrict__ A, float* __restrict__ B, int C, int N) {
    int c = blockIdx.x;
    float s = 0.f, q = 0.f;
    for (int i = threadIdx.x; i < nblk; i += 256) {
        s += part[(ll)i * 2 * C + c];
        q += part[(ll)i * 2 * C + C + c];
    }
    __shared__ float ls[256], lq[256];
    ls[threadIdx.x] = s; lq[threadIdx.x] = q;
    __syncthreads();
    for (int str = 128; str >= 1; str >>= 1) {
        if (threadIdx.x < str) {
            ls[threadIdx.x] += ls[threadIdx.x + str];
            lq[threadIdx.x] += lq[threadIdx.x + str];
        }
        __syncthreads();
    }
    if (threadIdx.x == 0) {
        float inv = 1.0f / (float)N;
        float mu = ls[0] * inv, var = lq[0] * inv - mu * mu;
        float a = g[c] * rsqrtf(var + 1e-5f);
        A[c] = a; B[c] = bb[c] - mu * a;
    }
}

template<int C>
__global__ void bnrelu_kernel(const short* __restrict__ x, const float* __restrict__ A,
                              const float* __restrict__ B, short* __restrict__ out, int N) {
    constexpr int CPR = C / 8;
    int i = blockIdx.x * 256 + threadIdx.x;
    if (i >= N * CPR) return;
    int r = i / CPR, ch = i - r * CPR;
    short8 v = *(const short8*)(x + (ll)r * C + ch * 8);
    short8 o;
    #pragma unroll
    for (int j = 0; j < 8; ++j) {
        int c = ch * 8 + j;
        float y = fmaf(bf2f(v[j]), A[c], B[c]);
        o[j] = f2bf(y > 0.f ? y : 0.f);
    }
    *(short8*)(out + (ll)r * C + ch * 8) = o;
}

__global__ void outk_kernel(const short* __restrict__ z, const float* __restrict__ A,
                            const float* __restrict__ B, const float* __restrict__ Wout,
                            float* __restrict__ out, int N) {
    __shared__ float w[64], sa[32], sb[32];
    if (threadIdx.x < 64) w[threadIdx.x] = Wout[threadIdx.x];
    if (threadIdx.x < 32) { sa[threadIdx.x] = A[threadIdx.x]; sb[threadIdx.x] = B[threadIdx.x]; }
    __syncthreads();
    int r = blockIdx.x * 256 + threadIdx.x;
    if (r >= N) return;
    const short* zp = z + (ll)r * 32;
    float o0 = 0.f, o1 = 0.f;
    #pragma unroll
    for (int s4 = 0; s4 < 4; ++s4) {
        short8 v = *(const short8*)(zp + s4 * 8);
        #pragma unroll
        for (int j = 0; j < 8; ++j) {
            int c = s4 * 8 + j;
            float y = fmaf(bf2f(v[j]), sa[c], sb[c]);
            y = y > 0.f ? y : 0.f;
            o0 = fmaf(y, w[2*c], o0);
            o1 = fmaf(y, w[2*c+1], o1);
        }
    }
    out[(ll)r * 2]     = o0;
    out[(ll)r * 2 + 1] = o1;
}

extern "C" void kernel_launch(void* const* d_in, const int* in_sizes, int n_in,
                              void* d_out, int out_size, void* d_ws, size_t ws_size,
                              hipStream_t stream) {
    const float* feats = (const float*)d_in[0];
    const float* W1 = (const float*)d_in[1];
    const float* W2 = (const float*)d_in[2];
    const float* W3 = (const float*)d_in[3];
    const float* W4 = (const float*)d_in[4];
    const float* W5 = (const float*)d_in[5];
    const float* Wout = (const float*)d_in[6];
    const float* g1 = (const float*)d_in[7],  *b1 = (const float*)d_in[8];
    const float* g2 = (const float*)d_in[9],  *b2 = (const float*)d_in[10];
    const float* g3 = (const float*)d_in[11], *b3 = (const float*)d_in[12];
    const float* g4 = (const float*)d_in[13], *b4 = (const float*)d_in[14];
    const float* g5 = (const float*)d_in[15], *b5 = (const float*)d_in[16];
    const int* nbr0 = (const int*)d_in[17];
    const int* nbr1 = (const int*)d_in[18];
    const int* nbr2 = (const int*)d_in[19];
    const int* up1_idx = (const int*)d_in[20];
    const int* up1_off = (const int*)d_in[21];
    const int* up0_idx = (const int*)d_in[22];
    const int* up0_off = (const int*)d_in[23];

    const int N0 = in_sizes[0] / 2;
    const int N1 = in_sizes[20];
    const int N2 = in_sizes[19] / 27;

    char* cur = (char*)d_ws;
    auto alloc = [&](size_t bytes) { char* p = cur; cur += (bytes + 255) & ~255ULL; return p; };
    auto cdiv = [](ll a, ll b) { return (int)((a + b - 1) / b); };

    float* stats = (float*)alloc(4096);
    float* A1 = stats,       *B1c = stats + 32;
    float* A2 = stats + 64,  *B2c = stats + 128;
    float* A3 = stats + 192, *B3c = stats + 320;
    float* A4 = stats + 448, *B4c = stats + 512;
    float* A5 = stats + 576, *B5c = stats + 608;
    short* zrow  = (short*)((char*)stats + 2560);   // 256 bf16 zeros
    int*   cnt4  = (int*)((char*)stats + 3072);
    int*   cur4  = (int*)((char*)stats + 3104);
    int*   cnt5  = (int*)((char*)stats + 3136);
    int*   cur5  = (int*)((char*)stats + 3168);
    int*   bas4  = (int*)((char*)stats + 3200);
    int*   bas5  = (int*)((char*)stats + 3264);

    float* part = (float*)alloc(2 * 1024 * 1024);   // per-block stats partials

    size_t zmax = (size_t)N1 * 64;
    if ((size_t)N0 * 32  > zmax) zmax = (size_t)N0 * 32;
    if ((size_t)N2 * 128 > zmax) zmax = (size_t)N2 * 128;
    short* zb  = (short*)alloc(zmax * 2);
    short* e1b = (short*)alloc((size_t)N0 * 32 * 2);
    short* e2b = (short*)alloc((size_t)N1 * 64 * 2);
    short* e3b = (short*)alloc((size_t)N2 * 128 * 2);
    short* d2b = (short*)alloc((size_t)N1 * 64 * 2);
    short* W1t = (short*)alloc(32 * 64 * 2);
    short* W2t = (short*)alloc((size_t)28 * 64 * 32 * 2);    // 28 k-tiles (27 = zeros)
    short* W3t = (short*)alloc((size_t)28 * 128 * 64 * 2);
    short* W4t = (short*)alloc((size_t)8 * 64 * 128 * 2);
    short* W5t = (short*)alloc((size_t)8 * 32 * 64 * 2);

    const int gridL4 = cdiv((ll)N1 + 512, 64);
    const int gridL5 = cdiv((ll)N0 + 512, 64);
    int* perm4 = (int*)alloc((size_t)gridL4 * 64 * 4);
    int* kofb4 = (int*)alloc((size_t)gridL4 * 4);
    int* perm5 = (int*)alloc((size_t)gridL5 * 64 * 4);
    int* kofb5 = (int*)alloc((size_t)gridL5 * 4);

    const int zoff1 = (int)((ll)((char*)zrow - (char*)e1b));
    const int zoff2 = (int)((ll)((char*)zrow - (char*)e2b));

    const int nblk1 = cdiv(N0, 64);
    const int nblk2 = cdiv(N1, 128);
    const int nblk3 = cdiv(N2, 128);

    hipMemsetAsync((char*)stats + 2560, 0, 640, stream);

    prep_kernel<<<cdiv(2048 + 28*2048 + 28*8192 + 65536 + 16384, 256), 256, 0, stream>>>(
        W1, W2, W3, W4, W5, W1t, W2t, W3t, W4t, W5t);

    // decoder permutation lists (merged kernels)
    {
        int gx = cdiv(N1 > N0 ? N1 : N0, 256);
        dcountB_kernel<<<dim3(gx, 2), 256, 0, stream>>>(up1_off, N1, cnt4, up0_off, N0, cnt5);
        dprefixB_kernel<<<2, 256, 0, stream>>>(cnt4, bas4, kofb4, perm4, gridL4,
                                               cnt5, bas5, kofb5, perm5, gridL5);
        dscatterB_kernel<<<dim3(gx, 2), 256, 0, stream>>>(up1_off, bas4, cur4, perm4, N1,
                                                          up0_off, bas5, cur5, perm5, N0);
    }

    // L1
    c1_kernel<<<nblk1, 256, 0, stream>>>(feats, nbr0, W1t, zb, part, N0);
    red2_kernel<<<32, 256, 0, stream>>>(part, nblk1, g1, b1, A1, B1c, 32, N0);
    bnrelu_kernel<32><<<cdiv((ll)N0 * 4, 256), 256, 0, stream>>>(zb, A1, B1c, e1b, N0);

    // L2: 128 rows x 64 cols, RG=2
    msconv7_kernel<32, 64, 2, 4><<<nblk2, 256, 0, stream>>>(e1b, nbr1, W2t, zb, part, N1, zoff1);
    red2_kernel<<<64, 256, 0, stream>>>(part, nblk2, g2, b2, A2, B2c, 64, N1);
    bnrelu_kernel<64><<<cdiv((ll)N1 * 8, 256), 256, 0, stream>>>(zb, A2, B2c, e2b, N1);

    // L3: 128 rows x 128 cols, RG=2
    msconv7_kernel<64, 128, 2, 3><<<nblk3, 256, 0, stream>>>(e2b, nbr2, W3t, zb, part, N2, zoff2);
    red2_kernel<<<128, 256, 0, stream>>>(part, nblk3, g3, b3, A3, B3c, 128, N2);
    bnrelu_kernel<128><<<cdiv((ll)N2 * 16, 256), 256, 0, stream>>>(zb, A3, B3c, e3b, N2);

    // L4
    gdec_kernel<128, 64><<<gridL4, 256, 0, stream>>>(e3b, perm4, kofb4, up1_idx, W4t, zrow, zb, part);
    red2_kernel<<<64, 256, 0, stream>>>(part, gridL4, g4, b4, A4, B4c, 64, N1);
    bnrelu_kernel<64><<<cdiv((ll)N1 * 8, 256), 256, 0, stream>>>(zb, A4, B4c, d2b, N1);

    // L5
    gdec_kernel<64, 32><<<gridL5, 256, 0, stream>>>(d2b, perm5, kofb5, up0_idx, W5t, zrow, zb, part);
    red2_kernel<<<32, 256, 0, stream>>>(part, gridL5, g5, b5, A5, B5c, 32, N0);
    outk_kernel<<<cdiv(N0, 256), 256, 0, stream>>>(zb, A5, B5c, Wout, (float*)d_out, N0);
}